// Round 8
// baseline (1778.634 us; speedup 1.0000x reference)
//
#include <hip/hip_runtime.h>
#include <cstdint>

typedef __attribute__((ext_vector_type(8))) short short8;
typedef __attribute__((ext_vector_type(4))) float f32x4;

__device__ __forceinline__ ushort f2bf(float x){
    uint32_t u = __float_as_uint(x);
    u = (u + 0x7FFFu + ((u >> 16) & 1u)) >> 16;
    return (ushort)u;
}

// ---------------- kernel 1: fp32 -> bf16 weight conversion ----------------
__global__ void k_conv(const float* __restrict__ W1, const float* __restrict__ W2,
                       const float* __restrict__ Emb,
                       ushort* __restrict__ W1b, ushort* __restrict__ W2b,
                       ushort* __restrict__ Eb){
    int i = blockIdx.x * 256 + threadIdx.x;   // grid 256 -> 65536
    W1b[i] = f2bf(W1[i]);
    W2b[i] = f2bf(W2[i]);
    Eb[i]  = f2bf(Emb[i]);
}

// -------- kernel 2: proj[v][h] = sum_e embed[v,e]*W_in[h,e]  (fp32) -------
__global__ void k_proj(const float* __restrict__ emb, const float* __restrict__ Win,
                       float* __restrict__ proj){
    __shared__ __align__(16) float se[256];
    int v = blockIdx.x, h = threadIdx.x;
    se[h] = emb[v*256 + h];
    __syncthreads();
    const float* wr = Win + h*256;
    float a0=0.f,a1=0.f,a2=0.f,a3=0.f;
    #pragma unroll
    for (int e = 0; e < 256; e += 4){
        float4 w = *(const float4*)(wr + e);
        a0 = fmaf(w.x, se[e+0], a0);
        a1 = fmaf(w.y, se[e+1], a1);
        a2 = fmaf(w.z, se[e+2], a2);
        a3 = fmaf(w.w, se[e+3], a3);
    }
    proj[v*256 + h] = (a0+a1)+(a2+a3);
}

// -------- kernel 2b: CSR build. W is ~90% sparse (~25.6 nz/row). ---------
// 256 blocks x 64 threads: block r compacts row r via ballot prefix-sum.
// ccol stores BYTE offsets (col*4). Rows padded to 56 with val=0,col=0.
__global__ void k_csr(const float* __restrict__ W, float* __restrict__ cval,
                      int* __restrict__ ccol, int* __restrict__ cnt){
    const int r = blockIdx.x, lane = threadIdx.x;   // 64 lanes
    int base = 0;
    for (int c = 0; c < 4; ++c){
        float w = W[r*256 + c*64 + lane];
        unsigned long long m = __ballot(w != 0.f);
        int pos = __popcll(m & ((1ull << lane) - 1ull));
        if (w != 0.f){
            int p = base + pos;
            if (p < 56){ cval[r*56 + p] = w; ccol[r*56 + p] = (c*64 + lane)*4; }
        }
        base += __popcll(m);
    }
    if (base > 56) base = 56;                       // P ~ 1e-10, safety clamp
    if (lane == 0) cnt[r] = base;
    for (int p = base + lane; p < 56; p += 64){ cval[r*56+p] = 0.f; ccol[r*56+p] = 0; }
}

// -------- kernel 2c: count-sort rows so waves get uniform nnz ------------
// sperm[slot] = row, sslot[row] = slot (inverse, for bank-reorder).
__global__ void k_rank(const int* __restrict__ cnt, int* __restrict__ sperm,
                       int* __restrict__ sslot){
    __shared__ int sc[256];
    int i = threadIdx.x;
    sc[i] = cnt[i];
    __syncthreads();
    int ci = sc[i], r = 0;
    for (int j = 0; j < 256; ++j){
        int cj = sc[j];
        r += (cj < ci) || (cj == ci && j < i);
    }
    sperm[r] = i;
    sslot[i] = r;
}

// -------- kernel 2d: bank-spreading reorder of each row's entries --------
// Within-row order is free (same sum). Sort row entries by bank (col%32),
// then rotate by s = ((lane&31)*cnt)>>5 where lane = sslot[row]&63 (the
// row's lane position in its k_recur wave). Result: at each gather slot k,
// the wave's 64 lanes read ~uniformly spread banks (2/bank = free, m136).
__global__ void k_sort(const float* __restrict__ cval, const int* __restrict__ ccol,
                       const int* __restrict__ cnt, const int* __restrict__ sslot,
                       float* __restrict__ cval2, int* __restrict__ ccol2){
    __shared__ int skey[56];
    const int r = blockIdx.x, p = threadIdx.x;      // 64 threads
    const int n = cnt[r];
    int colb = 0; float v = 0.f;
    if (p < 56){ colb = ccol[r*56 + p]; v = cval[r*56 + p]; }
    int col = colb >> 2;
    if (p < 56) skey[p] = (p < n) ? (((col & 31) << 9) | p) : 0x7fffffff;
    __syncthreads();
    if (p < n){
        int mykey = ((col & 31) << 9) | p;
        int rank = 0;
        #pragma unroll
        for (int q = 0; q < 56; ++q) rank += (skey[q] < mykey);
        int lane = sslot[r] & 63;
        int s = ((lane & 31) * n) >> 5;             // s in [0, n)
        int np = rank + n - s; if (np >= n) np -= n;
        ccol2[r*56 + np] = colb;
        cval2[r*56 + np] = v;
    } else if (p < 56){
        ccol2[r*56 + p] = 0; cval2[r*56 + p] = 0.f;
    }
}

// ---------------- kernel 3: ESN recurrence, sparse, 1 thread/row ---------
// 128 blocks (one per batch row) x 256 threads (4 waves). thread g owns row
// sperm[g]: all its ~26 (val,col) pairs in registers; per step ~26 LDS
// gathers + FMA, full epilogue per thread (no cross-lane reduce at all).
// t-loop unrolled x2 so the s_h double-buffer offset (0/1024B) is a
// compile-time constant folded into the ds_read immediate.
// u (proj) load software-pipelined one step ahead; hs store floats on vmcnt
// (the per-step barrier drains lgkmcnt only).
__global__ __launch_bounds__(256, 1) void k_recur(const int* __restrict__ idx,
        const float* cval, const int* ccol, const int* cnt, const int* sperm,
        const float* proj, ushort* hs){
    __shared__ __align__(16) float s_h[2][256];
    __shared__ int s_idx[2049];
    const int tid = threadIdx.x;                    // 0..255 = sorted slot
    const int b   = blockIdx.x;

    for (int i = tid; i < 2048; i += 256) s_idx[i] = idx[b*2048 + i];
    if (tid == 0) s_idx[2048] = 0;

    const int myrow = sperm[tid];
    const int mycnt = cnt[myrow];
    float val[56]; int colb[56];
    #pragma unroll
    for (int k = 0; k < 56; ++k){
        val[k]  = cval[myrow*56 + k];
        colb[k] = ccol[myrow*56 + k];
    }
    int kw = mycnt;
    kw = max(kw, __shfl_xor(kw, 1));  kw = max(kw, __shfl_xor(kw, 2));
    kw = max(kw, __shfl_xor(kw, 4));  kw = max(kw, __shfl_xor(kw, 8));
    kw = max(kw, __shfl_xor(kw, 16)); kw = max(kw, __shfl_xor(kw, 32));
    const int KW = __builtin_amdgcn_readfirstlane(kw);

    s_h[0][tid] = 0.f;
    __syncthreads();

    float h_prev = 0.f;
    ushort* hrow = hs + (size_t)b * 2048 * 256;
    const char* hb = (const char*)&s_h[0][0];
    char*       hw = (char*)&s_h[0][0];
    float u = proj[s_idx[0]*256 + myrow];

#define GATH(K, RO) acc = fmaf(val[K], *(const float*)(hb + (RO) + colb[K]), acc)
#define CH4(K, RO)  GATH(K,RO); GATH((K)+1,RO); GATH((K)+2,RO); GATH((K)+3,RO)
#define BODY(T, RO, WO)                                                       \
    {                                                                         \
        float u_nxt = proj[s_idx[(T)+1]*256 + myrow];                         \
        float acc = 0.f;                                                      \
        CH4(0, RO);                                                           \
        if (KW >  4){ CH4( 4, RO); }                                          \
        if (KW >  8){ CH4( 8, RO); }                                          \
        if (KW > 12){ CH4(12, RO); }                                          \
        if (KW > 16){ CH4(16, RO); }                                          \
        if (KW > 20){ CH4(20, RO); }                                          \
        if (KW > 24){ CH4(24, RO); }                                          \
        if (KW > 28){ CH4(28, RO); }                                          \
        if (KW > 32){ CH4(32, RO); }                                          \
        if (KW > 36){ CH4(36, RO); }                                          \
        if (KW > 40){ CH4(40, RO); }                                          \
        if (KW > 44){ CH4(44, RO); }                                          \
        if (KW > 48){ CH4(48, RO); }                                          \
        if (KW > 52){ CH4(52, RO); }                                          \
        float pre = acc + u;                                                  \
        pre = fminf(20.f, fmaxf(-20.f, pre));                                 \
        float e  = __expf(2.f*pre);                                           \
        float th = 1.f - __fdividef(2.f, e + 1.f);                            \
        float hn = 0.7f*h_prev + 0.3f*th;                                     \
        h_prev = hn;                                                          \
        *(float*)(hw + (WO) + 4*myrow) = hn;                                  \
        hrow[(size_t)(T)*256 + myrow] = f2bf(hn);                             \
        u = u_nxt;                                                            \
        asm volatile("s_waitcnt lgkmcnt(0)\n\ts_barrier" ::: "memory");       \
    }

    for (int t = 0; t < 2048; t += 2){
        BODY(t,   0,    1024);
        BODY(t+1, 1024, 0);
    }
#undef BODY
#undef CH4
#undef GATH
}

// ---------------- kernel 4: fused readout MLP + LN + lm_head --------------
// per block: 128 rows of BT. 512 threads = 8 waves, wave owns 16 rows.
// GEMM1 (swapped, D[e,m]) -> gelu -> A1_lds[m][e]
// GEMM2 (swapped, D[e2,m]) -> LN over e2 -> y_lds[m][e2] (overwrites A1)
// GEMM3 (unswapped, D[m,v]) -> fp32 out
__global__ __launch_bounds__(512) void k_readout(
        const ushort* __restrict__ hs,
        const ushort* __restrict__ W1b, const ushort* __restrict__ W2b,
        const ushort* __restrict__ Eb,
        const float* __restrict__ b1, const float* __restrict__ b2,
        const float* __restrict__ gamma, const float* __restrict__ beta,
        float* __restrict__ out){
    __shared__ __align__(16) char w_lds[65536];   // staged weight half: 128 rows x 256 bf16
    __shared__ __align__(16) char a_lds[65536];   // A1 / y tile: 128 rows x 256 bf16

    const int tid  = threadIdx.x;
    const int wid  = tid >> 6;
    const int lane = tid & 63;
    const int lr   = lane & 15;
    const int lg   = lane >> 4;
    const size_t m0 = (size_t)blockIdx.x * 128;
    const int ml   = wid*16 + lr;                 // this lane's m-row (local)

    // stage a 128x256 bf16 weight half into w_lds, XOR-swizzled
    auto stage = [&](const ushort* src){
        #pragma unroll
        for (int i = 0; i < 8; ++i){
            int off = (i*512 + tid) * 16;
            uint4 v = *(const uint4*)((const char*)src + off);
            int row = off >> 9;
            *(uint4*)(w_lds + (off ^ ((row & 7) << 4))) = v;
        }
    };
    // A-fragment of staged weight, tile n, k-chunk k0
    auto wfrag = [&](int n, int k0) -> short8 {
        int row  = n*16 + lr;
        int addr = (row << 9) + k0*64 + lg*16;
        addr ^= (row & 7) << 4;
        return __builtin_bit_cast(short8, *(const uint4*)(w_lds + addr));
    };
    // fragment of a_lds at own m-row, k-chunk k0
    auto afrag = [&](int k0) -> short8 {
        int addr = (ml << 9) + k0*64 + lg*16;
        addr ^= (ml & 7) << 4;
        return __builtin_bit_cast(short8, *(const uint4*)(a_lds + addr));
    };
    // write 4 consecutive e-values (8B) into a_lds[ml][ecol..ecol+3]
    auto awrite = [&](int ecol, f32x4 v){
        ushort4 pk;
        pk.x = f2bf(v[0]); pk.y = f2bf(v[1]); pk.z = f2bf(v[2]); pk.w = f2bf(v[3]);
        int addr = (ml << 9) + ecol*2;
        addr ^= (ml & 7) << 4;
        *(ushort4*)(a_lds + addr) = pk;
    };

    // ---- hs fragments straight from global (16B/lane, reused both halves) ----
    short8 hb[8];
    {
        const char* p = (const char*)(hs + (m0 + ml)*256) + lg*16;
        #pragma unroll
        for (int k0 = 0; k0 < 8; ++k0)
            hb[k0] = __builtin_bit_cast(short8, *(const uint4*)(p + k0*64));
    }

    // ================= GEMM1: A1 = gelu(hs @ W1.T + b1) =================
    #pragma unroll
    for (int h = 0; h < 2; ++h){
        __syncthreads();
        stage(W1b + h*128*256);
        __syncthreads();
        #pragma unroll
        for (int n = 0; n < 8; ++n){
            int eb = h*128 + n*16;
            float4 bi = *(const float4*)(b1 + eb + lg*4);
            f32x4 acc = {bi.x, bi.y, bi.z, bi.w};
            #pragma unroll
            for (int k0 = 0; k0 < 8; ++k0)
                acc = __builtin_amdgcn_mfma_f32_16x16x32_bf16(wfrag(n,k0), hb[k0], acc, 0,0,0);
            f32x4 g;
            #pragma unroll
            for (int q = 0; q < 4; ++q){
                float x = acc[q];
                g[q] = 0.5f*x*(1.f + erff(x*0.70710678118654752440f));
            }
            awrite(eb + lg*4, g);
        }
    }

    // ================= GEMM2: o = A1 @ W2.T + b2 =================
    short8 ab[8];
    __syncthreads();
    #pragma unroll
    for (int k0 = 0; k0 < 8; ++k0) ab[k0] = afrag(k0);
    f32x4 oacc[16];
    #pragma unroll
    for (int h = 0; h < 2; ++h){
        __syncthreads();
        stage(W2b + h*128*256);
        __syncthreads();
        #pragma unroll
        for (int n = 0; n < 8; ++n){
            int eb = h*128 + n*16;
            float4 bi = *(const float4*)(b2 + eb + lg*4);
            f32x4 acc = {bi.x, bi.y, bi.z, bi.w};
            #pragma unroll
            for (int k0 = 0; k0 < 8; ++k0)
                acc = __builtin_amdgcn_mfma_f32_16x16x32_bf16(wfrag(n,k0), ab[k0], acc, 0,0,0);
            oacc[h*8+n] = acc;
        }
    }

    // ================= LayerNorm over e2 (row dim of swapped D2) =================
    {
        float sum = 0.f, ss = 0.f;
        #pragma unroll
        for (int i = 0; i < 16; ++i){
            #pragma unroll
            for (int q = 0; q < 4; ++q){ float x = oacc[i][q]; sum += x; ss += x*x; }
        }
        sum += __shfl_xor(sum, 16); ss += __shfl_xor(ss, 16);
        sum += __shfl_xor(sum, 32); ss += __shfl_xor(ss, 32);
        float mu   = sum * (1.f/256.f);
        float var  = ss * (1.f/256.f) - mu*mu;
        float rstd = rsqrtf(var + 1e-5f);
        #pragma unroll
        for (int i = 0; i < 16; ++i){
            int ecol = (i >> 3)*128 + (i & 7)*16 + lg*4;
            float4 g4 = *(const float4*)(gamma + ecol);
            float4 t4 = *(const float4*)(beta + ecol);
            f32x4 y;
            y[0] = (oacc[i][0]-mu)*rstd*g4.x + t4.x;
            y[1] = (oacc[i][1]-mu)*rstd*g4.y + t4.y;
            y[2] = (oacc[i][2]-mu)*rstd*g4.z + t4.z;
            y[3] = (oacc[i][3]-mu)*rstd*g4.w + t4.w;
            awrite(ecol, y);
        }
    }

    // ================= GEMM3: logits = y @ embed.T (unswapped) =================
    __syncthreads();
    #pragma unroll
    for (int k0 = 0; k0 < 8; ++k0) ab[k0] = afrag(k0);   // y fragments
    #pragma unroll
    for (int h = 0; h < 2; ++h){
        __syncthreads();
        stage(Eb + h*128*256);
        __syncthreads();
        #pragma unroll
        for (int n = 0; n < 8; ++n){
            f32x4 acc = {0.f,0.f,0.f,0.f};
            #pragma unroll
            for (int k0 = 0; k0 < 8; ++k0)
                acc = __builtin_amdgcn_mfma_f32_16x16x32_bf16(ab[k0], wfrag(n,k0), acc, 0,0,0);
            int v = h*128 + n*16 + lr;
            float* op = out + (m0 + wid*16 + lg*4)*256 + v;
            op[0]   = acc[0];
            op[256] = acc[1];
            op[512] = acc[2];
            op[768] = acc[3];
        }
    }
}

// --------------------------------------------------------------------------
extern "C" void kernel_launch(void* const* d_in, const int* in_sizes, int n_in,
                              void* d_out, int out_size, void* d_ws, size_t ws_size,
                              hipStream_t stream){
    const int*   idx   = (const int*)d_in[0];
    const float* embed = (const float*)d_in[1];
    const float* W_in  = (const float*)d_in[2];
    const float* W     = (const float*)d_in[3];
    const float* W1    = (const float*)d_in[4];
    const float* b1    = (const float*)d_in[5];
    const float* W2    = (const float*)d_in[6];
    const float* b2    = (const float*)d_in[7];
    const float* gamma = (const float*)d_in[8];
    const float* beta  = (const float*)d_in[9];

    char* ws = (char*)d_ws;
    float*  proj  = (float*)ws;                   // 256 KB fp32
    ushort* W1b   = (ushort*)(ws + 262144);       // 128 KB bf16
    ushort* W2b   = (ushort*)(ws + 393216);       // 128 KB
    ushort* Eb    = (ushort*)(ws + 524288);       // 128 KB
    float*  cval  = (float*)(ws + 655360);        // 56 KB
    int*    ccol  = (int*)(ws + 712704);          // 56 KB
    int*    cnt   = (int*)(ws + 770048);          // 1 KB
    int*    sperm = (int*)(ws + 771072);          // 1 KB
    int*    sslot = (int*)(ws + 772096);          // 1 KB
    float*  cval2 = (float*)(ws + 786432);        // 56 KB (bank-reordered)
    int*    ccol2 = (int*)(ws + 843776);          // 56 KB
    ushort* hs    = (ushort*)(ws + 1048576);      // 134.2 MB bf16 [B*T, 256]
    if (ws_size < (size_t)135266304) return;      // ws too small -> recognizable absmax fail

    k_conv   <<<256, 256, 0, stream>>>(W1, W2, embed, W1b, W2b, Eb);
    k_proj   <<<256, 256, 0, stream>>>(embed, W_in, proj);
    k_csr    <<<256, 64, 0, stream>>>(W, cval, ccol, cnt);
    k_rank   <<<1, 256, 0, stream>>>(cnt, sperm, sslot);
    k_sort   <<<256, 64, 0, stream>>>(cval, ccol, cnt, sslot, cval2, ccol2);
    k_recur  <<<128, 256, 0, stream>>>(idx, cval2, ccol2, cnt, sperm, proj, hs);
    k_readout<<<2048, 512, 0, stream>>>(hs, W1b, W2b, Eb, b1, b2, gamma, beta, (float*)d_out);
}

// Round 9
// 1021.824 us; speedup vs baseline: 1.7406x; 1.7406x over previous
//
#include <hip/hip_runtime.h>
#include <cstdint>

typedef __attribute__((ext_vector_type(8))) short short8;
typedef __attribute__((ext_vector_type(4))) float f32x4;

__device__ __forceinline__ ushort f2bf(float x){
    uint32_t u = __float_as_uint(x);
    u = (u + 0x7FFFu + ((u >> 16) & 1u)) >> 16;
    return (ushort)u;
}

// ---------------- kernel 1: fp32 -> bf16 weight conversion ----------------
__global__ void k_conv(const float* __restrict__ W1, const float* __restrict__ W2,
                       const float* __restrict__ Emb,
                       ushort* __restrict__ W1b, ushort* __restrict__ W2b,
                       ushort* __restrict__ Eb){
    int i = blockIdx.x * 256 + threadIdx.x;   // grid 256 -> 65536
    W1b[i] = f2bf(W1[i]);
    W2b[i] = f2bf(W2[i]);
    Eb[i]  = f2bf(Emb[i]);
}

// -------- kernel 2: proj[v][h] = sum_e embed[v,e]*W_in[h,e]  (fp32) -------
__global__ void k_proj(const float* __restrict__ emb, const float* __restrict__ Win,
                       float* __restrict__ proj){
    __shared__ __align__(16) float se[256];
    int v = blockIdx.x, h = threadIdx.x;
    se[h] = emb[v*256 + h];
    __syncthreads();
    const float* wr = Win + h*256;
    float a0=0.f,a1=0.f,a2=0.f,a3=0.f;
    #pragma unroll
    for (int e = 0; e < 256; e += 4){
        float4 w = *(const float4*)(wr + e);
        a0 = fmaf(w.x, se[e+0], a0);
        a1 = fmaf(w.y, se[e+1], a1);
        a2 = fmaf(w.z, se[e+2], a2);
        a3 = fmaf(w.w, se[e+3], a3);
    }
    proj[v*256 + h] = (a0+a1)+(a2+a3);
}

// -------- kernel 2b: CSR build. W is ~90% sparse (~25.6 nz/row). ---------
// 256 blocks x 64 threads: block r compacts row r via ballot prefix-sum.
// ccol stores BYTE offsets (col*4). Rows padded to 56 with val=0,col=0.
__global__ void k_csr(const float* __restrict__ W, float* __restrict__ cval,
                      int* __restrict__ ccol, int* __restrict__ cnt){
    const int r = blockIdx.x, lane = threadIdx.x;   // 64 lanes
    int base = 0;
    for (int c = 0; c < 4; ++c){
        float w = W[r*256 + c*64 + lane];
        unsigned long long m = __ballot(w != 0.f);
        int pos = __popcll(m & ((1ull << lane) - 1ull));
        if (w != 0.f){
            int p = base + pos;
            if (p < 56){ cval[r*56 + p] = w; ccol[r*56 + p] = (c*64 + lane)*4; }
        }
        base += __popcll(m);
    }
    if (base > 56) base = 56;                       // P ~ 1e-10, safety clamp
    if (lane == 0) cnt[r] = base;
    for (int p = base + lane; p < 56; p += 64){ cval[r*56+p] = 0.f; ccol[r*56+p] = 0; }
}

// -------- kernel 2c: count-sort rows so waves get uniform nnz ------------
__global__ void k_rank(const int* __restrict__ cnt, int* __restrict__ sperm){
    __shared__ int sc[256];
    int i = threadIdx.x;
    sc[i] = cnt[i];
    __syncthreads();
    int ci = sc[i], r = 0;
    for (int j = 0; j < 256; ++j){
        int cj = sc[j];
        r += (cj < ci) || (cj == ci && j < i);
    }
    sperm[r] = i;
}

// ---------------- kernel 3: ESN recurrence, sparse, 2-way TIME SPLIT -----
// 256 blocks = (half, batch): half 0 computes t in [0,1024); half 1 starts
// from h=0 at t=640 (384 warmup steps, contraction ~0.96^384 ~ 4e-7 kills
// the initial-condition error) and writes t in [1024,2048). Critical path
// 1408 steps instead of 2048 (1.45x).
// Per block: 512 threads (8 waves, 2/SIMD for DS latency hiding - round 8
// showed 1 wave/SIMD is 1.4x worse). 2 threads per h-row, thread owns ~13
// (val,col-byte) pairs in registers; per step: LDS gather + FMA in two
// independent chains, shfl_xor(1) combine, both subs compute tanh, sub 0
// stores. One lgkmcnt-only barrier per step (correct: reads complete before
// each wave's barrier arrival; vmcnt (hs store) intentionally NOT drained).
__global__ __launch_bounds__(512, 2) void k_recur(const int* __restrict__ idx,
        const float* cval, const int* ccol, const int* cnt, const int* sperm,
        const float* proj, ushort* hs){
    __shared__ __align__(16) float s_h[2][256];
    __shared__ int s_idx[2049];
    const int tid  = threadIdx.x;
    const int b    = blockIdx.x & 127;
    const int half = blockIdx.x >> 7;
    const int t0   = half ? 640  : 0;     // 1024 - 384 warmup
    const int t1   = half ? 2048 : 1024;
    const int tw   = half ? 1024 : 0;     // first written step
    const int sub  = tid & 1;
    const int g    = tid >> 1;

    for (int i = tid; i < 2048; i += 512) s_idx[i] = idx[b*2048 + i];
    if (tid == 0) s_idx[2048] = 0;

    const int myrow = sperm[g];
    const int mycnt = cnt[myrow];
    float val[28]; int colb[28];
    #pragma unroll
    for (int k = 0; k < 28; ++k){
        int n = sub + 2*k;
        val[k]  = cval[myrow*56 + n];
        colb[k] = ccol[myrow*56 + n];
    }
    int kw = (mycnt + 1 - sub) >> 1;               // my entry count
    kw = max(kw, __shfl_xor(kw, 1));  kw = max(kw, __shfl_xor(kw, 2));
    kw = max(kw, __shfl_xor(kw, 4));  kw = max(kw, __shfl_xor(kw, 8));
    kw = max(kw, __shfl_xor(kw, 16)); kw = max(kw, __shfl_xor(kw, 32));
    const int KW = __builtin_amdgcn_readfirstlane(kw);

    if (tid < 256) s_h[0][tid] = 0.f;
    __syncthreads();

    float h_prev = 0.f;
    ushort* hrow = hs + (size_t)b * 2048 * 256;
    const char* hb = (const char*)&s_h[0][0];
    char*       hw = (char*)&s_h[0][0];
    float u = 0.f;
    if (sub == 0) u = proj[s_idx[t0]*256 + myrow];

#define GATH(K, RO, A) A = fmaf(val[K], *(const float*)(hb + (RO) + colb[K]), A)
#define CH4(K, RO, A)  GATH(K,RO,A); GATH((K)+1,RO,A); GATH((K)+2,RO,A); GATH((K)+3,RO,A)
#define BODY(T, RO, WO)                                                       \
    {                                                                         \
        float u_nxt = 0.f;                                                    \
        if (sub == 0) u_nxt = proj[s_idx[(T)+1]*256 + myrow];                 \
        float acc0 = 0.f, acc1 = 0.f;                                         \
        CH4(0, RO, acc0);                                                     \
        if (KW >  4){ CH4( 4, RO, acc1); }                                    \
        if (KW >  8){ CH4( 8, RO, acc0); }                                    \
        if (KW > 12){ CH4(12, RO, acc1); }                                    \
        if (KW > 16){ CH4(16, RO, acc0); }                                    \
        if (KW > 20){ CH4(20, RO, acc1); }                                    \
        if (KW > 24){ CH4(24, RO, acc0); }                                    \
        float acc = acc0 + acc1;                                              \
        acc += __shfl_xor(acc, 1);                                            \
        float pre = acc + u;                                                  \
        pre = fminf(20.f, fmaxf(-20.f, pre));                                 \
        float e  = __expf(2.f*pre);                                           \
        float th = 1.f - __fdividef(2.f, e + 1.f);                            \
        float hn = 0.7f*h_prev + 0.3f*th;                                     \
        h_prev = hn;                                                          \
        if (sub == 0){                                                        \
            *(float*)(hw + (WO) + 4*myrow) = hn;                              \
            if ((T) >= tw) hrow[(size_t)(T)*256 + myrow] = f2bf(hn);          \
        }                                                                     \
        u = u_nxt;                                                            \
        asm volatile("s_waitcnt lgkmcnt(0)\n\ts_barrier" ::: "memory");       \
    }

    for (int t = t0; t < t1; t += 2){
        BODY(t,   0,    1024);
        BODY(t+1, 1024, 0);
    }
#undef BODY
#undef CH4
#undef GATH
}

// ---------------- kernel 4: fused readout MLP + LN + lm_head --------------
// per block: 128 rows of BT. 512 threads = 8 waves, wave owns 16 rows.
// GEMM1 (swapped, D[e,m]) -> gelu -> A1_lds[m][e]
// GEMM2 (swapped, D[e2,m]) -> LN over e2 -> y_lds[m][e2] (overwrites A1)
// GEMM3 (unswapped, D[m,v]) -> fp32 out
__global__ __launch_bounds__(512) void k_readout(
        const ushort* __restrict__ hs,
        const ushort* __restrict__ W1b, const ushort* __restrict__ W2b,
        const ushort* __restrict__ Eb,
        const float* __restrict__ b1, const float* __restrict__ b2,
        const float* __restrict__ gamma, const float* __restrict__ beta,
        float* __restrict__ out){
    __shared__ __align__(16) char w_lds[65536];   // staged weight half: 128 rows x 256 bf16
    __shared__ __align__(16) char a_lds[65536];   // A1 / y tile: 128 rows x 256 bf16

    const int tid  = threadIdx.x;
    const int wid  = tid >> 6;
    const int lane = tid & 63;
    const int lr   = lane & 15;
    const int lg   = lane >> 4;
    const size_t m0 = (size_t)blockIdx.x * 128;
    const int ml   = wid*16 + lr;                 // this lane's m-row (local)

    // stage a 128x256 bf16 weight half into w_lds, XOR-swizzled
    auto stage = [&](const ushort* src){
        #pragma unroll
        for (int i = 0; i < 8; ++i){
            int off = (i*512 + tid) * 16;
            uint4 v = *(const uint4*)((const char*)src + off);
            int row = off >> 9;
            *(uint4*)(w_lds + (off ^ ((row & 7) << 4))) = v;
        }
    };
    // A-fragment of staged weight, tile n, k-chunk k0
    auto wfrag = [&](int n, int k0) -> short8 {
        int row  = n*16 + lr;
        int addr = (row << 9) + k0*64 + lg*16;
        addr ^= (row & 7) << 4;
        return __builtin_bit_cast(short8, *(const uint4*)(w_lds + addr));
    };
    // fragment of a_lds at own m-row, k-chunk k0
    auto afrag = [&](int k0) -> short8 {
        int addr = (ml << 9) + k0*64 + lg*16;
        addr ^= (ml & 7) << 4;
        return __builtin_bit_cast(short8, *(const uint4*)(a_lds + addr));
    };
    // write 4 consecutive e-values (8B) into a_lds[ml][ecol..ecol+3]
    auto awrite = [&](int ecol, f32x4 v){
        ushort4 pk;
        pk.x = f2bf(v[0]); pk.y = f2bf(v[1]); pk.z = f2bf(v[2]); pk.w = f2bf(v[3]);
        int addr = (ml << 9) + ecol*2;
        addr ^= (ml & 7) << 4;
        *(ushort4*)(a_lds + addr) = pk;
    };

    // ---- hs fragments straight from global (16B/lane, reused both halves) ----
    short8 hb[8];
    {
        const char* p = (const char*)(hs + (m0 + ml)*256) + lg*16;
        #pragma unroll
        for (int k0 = 0; k0 < 8; ++k0)
            hb[k0] = __builtin_bit_cast(short8, *(const uint4*)(p + k0*64));
    }

    // ================= GEMM1: A1 = gelu(hs @ W1.T + b1) =================
    #pragma unroll
    for (int h = 0; h < 2; ++h){
        __syncthreads();
        stage(W1b + h*128*256);
        __syncthreads();
        #pragma unroll
        for (int n = 0; n < 8; ++n){
            int eb = h*128 + n*16;
            float4 bi = *(const float4*)(b1 + eb + lg*4);
            f32x4 acc = {bi.x, bi.y, bi.z, bi.w};
            #pragma unroll
            for (int k0 = 0; k0 < 8; ++k0)
                acc = __builtin_amdgcn_mfma_f32_16x16x32_bf16(wfrag(n,k0), hb[k0], acc, 0,0,0);
            f32x4 g;
            #pragma unroll
            for (int q = 0; q < 4; ++q){
                float x = acc[q];
                g[q] = 0.5f*x*(1.f + erff(x*0.70710678118654752440f));
            }
            awrite(eb + lg*4, g);
        }
    }

    // ================= GEMM2: o = A1 @ W2.T + b2 =================
    short8 ab[8];
    __syncthreads();
    #pragma unroll
    for (int k0 = 0; k0 < 8; ++k0) ab[k0] = afrag(k0);
    f32x4 oacc[16];
    #pragma unroll
    for (int h = 0; h < 2; ++h){
        __syncthreads();
        stage(W2b + h*128*256);
        __syncthreads();
        #pragma unroll
        for (int n = 0; n < 8; ++n){
            int eb = h*128 + n*16;
            float4 bi = *(const float4*)(b2 + eb + lg*4);
            f32x4 acc = {bi.x, bi.y, bi.z, bi.w};
            #pragma unroll
            for (int k0 = 0; k0 < 8; ++k0)
                acc = __builtin_amdgcn_mfma_f32_16x16x32_bf16(wfrag(n,k0), ab[k0], acc, 0,0,0);
            oacc[h*8+n] = acc;
        }
    }

    // ================= LayerNorm over e2 (row dim of swapped D2) =================
    {
        float sum = 0.f, ss = 0.f;
        #pragma unroll
        for (int i = 0; i < 16; ++i){
            #pragma unroll
            for (int q = 0; q < 4; ++q){ float x = oacc[i][q]; sum += x; ss += x*x; }
        }
        sum += __shfl_xor(sum, 16); ss += __shfl_xor(ss, 16);
        sum += __shfl_xor(sum, 32); ss += __shfl_xor(ss, 32);
        float mu   = sum * (1.f/256.f);
        float var  = ss * (1.f/256.f) - mu*mu;
        float rstd = rsqrtf(var + 1e-5f);
        #pragma unroll
        for (int i = 0; i < 16; ++i){
            int ecol = (i >> 3)*128 + (i & 7)*16 + lg*4;
            float4 g4 = *(const float4*)(gamma + ecol);
            float4 t4 = *(const float4*)(beta + ecol);
            f32x4 y;
            y[0] = (oacc[i][0]-mu)*rstd*g4.x + t4.x;
            y[1] = (oacc[i][1]-mu)*rstd*g4.y + t4.y;
            y[2] = (oacc[i][2]-mu)*rstd*g4.z + t4.z;
            y[3] = (oacc[i][3]-mu)*rstd*g4.w + t4.w;
            awrite(ecol, y);
        }
    }

    // ================= GEMM3: logits = y @ embed.T (unswapped) =================
    __syncthreads();
    #pragma unroll
    for (int k0 = 0; k0 < 8; ++k0) ab[k0] = afrag(k0);   // y fragments
    #pragma unroll
    for (int h = 0; h < 2; ++h){
        __syncthreads();
        stage(Eb + h*128*256);
        __syncthreads();
        #pragma unroll
        for (int n = 0; n < 8; ++n){
            f32x4 acc = {0.f,0.f,0.f,0.f};
            #pragma unroll
            for (int k0 = 0; k0 < 8; ++k0)
                acc = __builtin_amdgcn_mfma_f32_16x16x32_bf16(ab[k0], wfrag(n,k0), acc, 0,0,0);
            int v = h*128 + n*16 + lr;
            float* op = out + (m0 + wid*16 + lg*4)*256 + v;
            op[0]   = acc[0];
            op[256] = acc[1];
            op[512] = acc[2];
            op[768] = acc[3];
        }
    }
}

// --------------------------------------------------------------------------
extern "C" void kernel_launch(void* const* d_in, const int* in_sizes, int n_in,
                              void* d_out, int out_size, void* d_ws, size_t ws_size,
                              hipStream_t stream){
    const int*   idx   = (const int*)d_in[0];
    const float* embed = (const float*)d_in[1];
    const float* W_in  = (const float*)d_in[2];
    const float* W     = (const float*)d_in[3];
    const float* W1    = (const float*)d_in[4];
    const float* b1    = (const float*)d_in[5];
    const float* W2    = (const float*)d_in[6];
    const float* b2    = (const float*)d_in[7];
    const float* gamma = (const float*)d_in[8];
    const float* beta  = (const float*)d_in[9];

    char* ws = (char*)d_ws;
    float*  proj  = (float*)ws;                   // 256 KB fp32
    ushort* W1b   = (ushort*)(ws + 262144);       // 128 KB bf16
    ushort* W2b   = (ushort*)(ws + 393216);       // 128 KB
    ushort* Eb    = (ushort*)(ws + 524288);       // 128 KB
    float*  cval  = (float*)(ws + 655360);        // 56 KB
    int*    ccol  = (int*)(ws + 712704);          // 56 KB
    int*    cnt   = (int*)(ws + 770048);          // 1 KB
    int*    sperm = (int*)(ws + 771072);          // 1 KB
    ushort* hs    = (ushort*)(ws + 1048576);      // 134.2 MB bf16 [B*T, 256]
    if (ws_size < (size_t)135266304) return;      // ws too small -> recognizable absmax fail

    k_conv   <<<256, 256, 0, stream>>>(W1, W2, embed, W1b, W2b, Eb);
    k_proj   <<<256, 256, 0, stream>>>(embed, W_in, proj);
    k_csr    <<<256, 64, 0, stream>>>(W, cval, ccol, cnt);
    k_rank   <<<1, 256, 0, stream>>>(cnt, sperm);
    k_recur  <<<256, 512, 0, stream>>>(idx, cval, ccol, cnt, sperm, proj, hs);
    k_readout<<<2048, 512, 0, stream>>>(hs, W1b, W2b, Eb, b1, b2, gamma, beta, (float*)d_out);
}

// Round 10
// 751.757 us; speedup vs baseline: 2.3660x; 1.3592x over previous
//
#include <hip/hip_runtime.h>
#include <cstdint>

typedef __attribute__((ext_vector_type(8))) short short8;
typedef __attribute__((ext_vector_type(4))) float f32x4;

__device__ __forceinline__ ushort f2bf(float x){
    uint32_t u = __float_as_uint(x);
    u = (u + 0x7FFFu + ((u >> 16) & 1u)) >> 16;
    return (ushort)u;
}

// ---------------- kernel 1: fp32 -> bf16 weight conversion ----------------
__global__ void k_conv(const float* __restrict__ W1, const float* __restrict__ W2,
                       const float* __restrict__ Emb,
                       ushort* __restrict__ W1b, ushort* __restrict__ W2b,
                       ushort* __restrict__ Eb){
    int i = blockIdx.x * 256 + threadIdx.x;   // grid 256 -> 65536
    W1b[i] = f2bf(W1[i]);
    W2b[i] = f2bf(W2[i]);
    Eb[i]  = f2bf(Emb[i]);
}

// -------- kernel 2: proj[v][h] = sum_e embed[v,e]*W_in[h,e]  (fp32) -------
__global__ void k_proj(const float* __restrict__ emb, const float* __restrict__ Win,
                       float* __restrict__ proj){
    __shared__ __align__(16) float se[256];
    int v = blockIdx.x, h = threadIdx.x;
    se[h] = emb[v*256 + h];
    __syncthreads();
    const float* wr = Win + h*256;
    float a0=0.f,a1=0.f,a2=0.f,a3=0.f;
    #pragma unroll
    for (int e = 0; e < 256; e += 4){
        float4 w = *(const float4*)(wr + e);
        a0 = fmaf(w.x, se[e+0], a0);
        a1 = fmaf(w.y, se[e+1], a1);
        a2 = fmaf(w.z, se[e+2], a2);
        a3 = fmaf(w.w, se[e+3], a3);
    }
    proj[v*256 + h] = (a0+a1)+(a2+a3);
}

// -------- kernel 2b: CSR build. W is ~90% sparse (~25.6 nz/row). ---------
// 256 blocks x 64 threads: block r compacts row r via ballot prefix-sum.
// ccol stores BYTE offsets (col*4). Rows padded to 56 with val=0,col=0.
__global__ void k_csr(const float* __restrict__ W, float* __restrict__ cval,
                      int* __restrict__ ccol, int* __restrict__ cnt){
    const int r = blockIdx.x, lane = threadIdx.x;   // 64 lanes
    int base = 0;
    for (int c = 0; c < 4; ++c){
        float w = W[r*256 + c*64 + lane];
        unsigned long long m = __ballot(w != 0.f);
        int pos = __popcll(m & ((1ull << lane) - 1ull));
        if (w != 0.f){
            int p = base + pos;
            if (p < 56){ cval[r*56 + p] = w; ccol[r*56 + p] = (c*64 + lane)*4; }
        }
        base += __popcll(m);
    }
    if (base > 56) base = 56;                       // P ~ 1e-10, safety clamp
    if (lane == 0) cnt[r] = base;
    for (int p = base + lane; p < 56; p += 64){ cval[r*56+p] = 0.f; ccol[r*56+p] = 0; }
}

// -------- kernel 2c: count-sort rows so waves get uniform nnz ------------
__global__ void k_rank(const int* __restrict__ cnt, int* __restrict__ sperm){
    __shared__ int sc[256];
    int i = threadIdx.x;
    sc[i] = cnt[i];
    __syncthreads();
    int ci = sc[i], r = 0;
    for (int j = 0; j < 256; ++j){
        int cj = sc[j];
        r += (cj < ci) || (cj == ci && j < i);
    }
    sperm[r] = i;
}

// ------- kernel 3: ESN recurrence, sparse, batch-PAIRED + 4-way SPLIT ----
// 256 blocks = (segment q in [0,4)) x (batch pair p in [0,64)). Segment q
// writes t in [512q, 512q+512); q>0 starts from h=0 at t0=512q-384 (384
// warmup steps; contraction makes the h=0 initial-condition error ~1e-6,
// invisible vs the bf16 floor - verified round 9, absmax unchanged).
// Critical path: 896 steps (was 1408).
//
// Batch pairing: the two batch rows' h vectors are INTERLEAVED in LDS
// (h[col*8 + 4*x], x = batch-in-pair), so ONE ds_read_b64 gathers h[col]
// for both batches -> the DS-issue-bound gather serves 2 rows per instr
// (round 7/8 showed DS instruction issue, not BW, is the wall).
// 512 threads (8 waves, 2/SIMD - round 8 showed 1 wave/SIMD exposes DS
// latency). 2 threads per h-row: sub=tid&1 owns CSR entries sub,sub+2,...;
// after two shfl_xor(1) combines, sub 0 finalizes batch a, sub 1 batch b
// (parallel epilogue, parallel h-write/hs-store).
// Straight-line literal-indexed gather (SROA-safe, round 6/7 lesson);
// KW wave-uniform via count-sorted rows + readfirstlane.
__global__ __launch_bounds__(512, 2) void k_recur(const int* __restrict__ idx,
        const float* cval, const int* ccol, const int* cnt, const int* sperm,
        const float* proj, ushort* hs){
    __shared__ __align__(16) float s_h[2][512];   // [dbuf][col*2 + x]
    __shared__ int s_idx[2][900];
    const int tid  = threadIdx.x;
    const int q    = blockIdx.x >> 6;     // time segment
    const int p    = blockIdx.x & 63;     // batch pair
    const int t0   = q ? (512*q - 384) : 0;
    const int t1   = 512*q + 512;
    const int tw   = 512*q;               // first written step
    const int sub  = tid & 1;
    const int g    = tid >> 1;
    const int len  = t1 - t0;

    for (int i = tid; i < len; i += 512){
        s_idx[0][i] = idx[(2*p    )*2048 + t0 + i];
        s_idx[1][i] = idx[(2*p + 1)*2048 + t0 + i];
    }
    if (tid == 0){ s_idx[0][len] = 0; s_idx[1][len] = 0; }

    const int myrow = sperm[g];
    const int mycnt = cnt[myrow];
    float val[28]; int colb[28];
    #pragma unroll
    for (int k = 0; k < 28; ++k){
        int n = sub + 2*k;
        val[k]  = cval[myrow*56 + n];
        colb[k] = 2*ccol[myrow*56 + n];   // col*4 -> col*8 (paired layout)
    }
    int kw = (mycnt + 1 - sub) >> 1;               // my entry count
    kw = max(kw, __shfl_xor(kw, 1));  kw = max(kw, __shfl_xor(kw, 2));
    kw = max(kw, __shfl_xor(kw, 4));  kw = max(kw, __shfl_xor(kw, 8));
    kw = max(kw, __shfl_xor(kw, 16)); kw = max(kw, __shfl_xor(kw, 32));
    const int KW = __builtin_amdgcn_readfirstlane(kw);

    s_h[0][tid] = 0.f;                    // zeroes both batches (512 floats)
    __syncthreads();

    float h_prev = 0.f;
    ushort* hrow = hs + (size_t)(2*p + sub) * 2048 * 256;  // my batch row
    const char* hb = (const char*)&s_h[0][0];
    char*       hw = (char*)&s_h[0][0];
    float u = proj[s_idx[sub][0]*256 + myrow];

#define GATH(K, RO)                                                           \
    { float2 hv = *(const float2*)(hb + (RO) + colb[K]);                      \
      acc_a = fmaf(val[K], hv.x, acc_a);                                      \
      acc_b = fmaf(val[K], hv.y, acc_b); }
#define CH4(K, RO)  GATH(K,RO) GATH((K)+1,RO) GATH((K)+2,RO) GATH((K)+3,RO)
#define BODY(T, RO, WO)                                                       \
    {                                                                         \
        float u_nxt = proj[s_idx[sub][(T)+1 - t0]*256 + myrow];               \
        float acc_a = 0.f, acc_b = 0.f;                                       \
        CH4(0, RO);                                                           \
        if (KW >  4){ CH4( 4, RO); }                                          \
        if (KW >  8){ CH4( 8, RO); }                                          \
        if (KW > 12){ CH4(12, RO); }                                          \
        if (KW > 16){ CH4(16, RO); }                                          \
        if (KW > 20){ CH4(20, RO); }                                          \
        if (KW > 24){ CH4(24, RO); }                                          \
        acc_a += __shfl_xor(acc_a, 1);                                        \
        acc_b += __shfl_xor(acc_b, 1);                                        \
        float pre = (sub ? acc_b : acc_a) + u;                                \
        pre = fminf(20.f, fmaxf(-20.f, pre));                                 \
        float e  = __expf(2.f*pre);                                           \
        float th = 1.f - __fdividef(2.f, e + 1.f);                            \
        float hn = 0.7f*h_prev + 0.3f*th;                                     \
        h_prev = hn;                                                          \
        *(float*)(hw + (WO) + 8*myrow + 4*sub) = hn;                          \
        if ((T) >= tw) hrow[(size_t)(T)*256 + myrow] = f2bf(hn);              \
        u = u_nxt;                                                            \
        asm volatile("s_waitcnt lgkmcnt(0)\n\ts_barrier" ::: "memory");       \
    }

    for (int t = t0; t < t1; t += 2){
        BODY(t,   0,    2048);
        BODY(t+1, 2048, 0);
    }
#undef BODY
#undef CH4
#undef GATH
}

// ---------------- kernel 4: fused readout MLP + LN + lm_head --------------
// per block: 128 rows of BT. 512 threads = 8 waves, wave owns 16 rows.
// GEMM1 (swapped, D[e,m]) -> gelu -> A1_lds[m][e]
// GEMM2 (swapped, D[e2,m]) -> LN over e2 -> y_lds[m][e2] (overwrites A1)
// GEMM3 (unswapped, D[m,v]) -> fp32 out
__global__ __launch_bounds__(512) void k_readout(
        const ushort* __restrict__ hs,
        const ushort* __restrict__ W1b, const ushort* __restrict__ W2b,
        const ushort* __restrict__ Eb,
        const float* __restrict__ b1, const float* __restrict__ b2,
        const float* __restrict__ gamma, const float* __restrict__ beta,
        float* __restrict__ out){
    __shared__ __align__(16) char w_lds[65536];   // staged weight half: 128 rows x 256 bf16
    __shared__ __align__(16) char a_lds[65536];   // A1 / y tile: 128 rows x 256 bf16

    const int tid  = threadIdx.x;
    const int wid  = tid >> 6;
    const int lane = tid & 63;
    const int lr   = lane & 15;
    const int lg   = lane >> 4;
    const size_t m0 = (size_t)blockIdx.x * 128;
    const int ml   = wid*16 + lr;                 // this lane's m-row (local)

    // stage a 128x256 bf16 weight half into w_lds, XOR-swizzled
    auto stage = [&](const ushort* src){
        #pragma unroll
        for (int i = 0; i < 8; ++i){
            int off = (i*512 + tid) * 16;
            uint4 v = *(const uint4*)((const char*)src + off);
            int row = off >> 9;
            *(uint4*)(w_lds + (off ^ ((row & 7) << 4))) = v;
        }
    };
    // A-fragment of staged weight, tile n, k-chunk k0
    auto wfrag = [&](int n, int k0) -> short8 {
        int row  = n*16 + lr;
        int addr = (row << 9) + k0*64 + lg*16;
        addr ^= (row & 7) << 4;
        return __builtin_bit_cast(short8, *(const uint4*)(w_lds + addr));
    };
    // fragment of a_lds at own m-row, k-chunk k0
    auto afrag = [&](int k0) -> short8 {
        int addr = (ml << 9) + k0*64 + lg*16;
        addr ^= (ml & 7) << 4;
        return __builtin_bit_cast(short8, *(const uint4*)(a_lds + addr));
    };
    // write 4 consecutive e-values (8B) into a_lds[ml][ecol..ecol+3]
    auto awrite = [&](int ecol, f32x4 v){
        ushort4 pk;
        pk.x = f2bf(v[0]); pk.y = f2bf(v[1]); pk.z = f2bf(v[2]); pk.w = f2bf(v[3]);
        int addr = (ml << 9) + ecol*2;
        addr ^= (ml & 7) << 4;
        *(ushort4*)(a_lds + addr) = pk;
    };

    // ---- hs fragments straight from global (16B/lane, reused both halves) ----
    short8 hb[8];
    {
        const char* p = (const char*)(hs + (m0 + ml)*256) + lg*16;
        #pragma unroll
        for (int k0 = 0; k0 < 8; ++k0)
            hb[k0] = __builtin_bit_cast(short8, *(const uint4*)(p + k0*64));
    }

    // ================= GEMM1: A1 = gelu(hs @ W1.T + b1) =================
    #pragma unroll
    for (int h = 0; h < 2; ++h){
        __syncthreads();
        stage(W1b + h*128*256);
        __syncthreads();
        #pragma unroll
        for (int n = 0; n < 8; ++n){
            int eb = h*128 + n*16;
            float4 bi = *(const float4*)(b1 + eb + lg*4);
            f32x4 acc = {bi.x, bi.y, bi.z, bi.w};
            #pragma unroll
            for (int k0 = 0; k0 < 8; ++k0)
                acc = __builtin_amdgcn_mfma_f32_16x16x32_bf16(wfrag(n,k0), hb[k0], acc, 0,0,0);
            f32x4 g;
            #pragma unroll
            for (int q = 0; q < 4; ++q){
                float x = acc[q];
                g[q] = 0.5f*x*(1.f + erff(x*0.70710678118654752440f));
            }
            awrite(eb + lg*4, g);
        }
    }

    // ================= GEMM2: o = A1 @ W2.T + b2 =================
    short8 ab[8];
    __syncthreads();
    #pragma unroll
    for (int k0 = 0; k0 < 8; ++k0) ab[k0] = afrag(k0);
    f32x4 oacc[16];
    #pragma unroll
    for (int h = 0; h < 2; ++h){
        __syncthreads();
        stage(W2b + h*128*256);
        __syncthreads();
        #pragma unroll
        for (int n = 0; n < 8; ++n){
            int eb = h*128 + n*16;
            float4 bi = *(const float4*)(b2 + eb + lg*4);
            f32x4 acc = {bi.x, bi.y, bi.z, bi.w};
            #pragma unroll
            for (int k0 = 0; k0 < 8; ++k0)
                acc = __builtin_amdgcn_mfma_f32_16x16x32_bf16(wfrag(n,k0), ab[k0], acc, 0,0,0);
            oacc[h*8+n] = acc;
        }
    }

    // ================= LayerNorm over e2 (row dim of swapped D2) =================
    {
        float sum = 0.f, ss = 0.f;
        #pragma unroll
        for (int i = 0; i < 16; ++i){
            #pragma unroll
            for (int q = 0; q < 4; ++q){ float x = oacc[i][q]; sum += x; ss += x*x; }
        }
        sum += __shfl_xor(sum, 16); ss += __shfl_xor(ss, 16);
        sum += __shfl_xor(sum, 32); ss += __shfl_xor(ss, 32);
        float mu   = sum * (1.f/256.f);
        float var  = ss * (1.f/256.f) - mu*mu;
        float rstd = rsqrtf(var + 1e-5f);
        #pragma unroll
        for (int i = 0; i < 16; ++i){
            int ecol = (i >> 3)*128 + (i & 7)*16 + lg*4;
            float4 g4 = *(const float4*)(gamma + ecol);
            float4 t4 = *(const float4*)(beta + ecol);
            f32x4 y;
            y[0] = (oacc[i][0]-mu)*rstd*g4.x + t4.x;
            y[1] = (oacc[i][1]-mu)*rstd*g4.y + t4.y;
            y[2] = (oacc[i][2]-mu)*rstd*g4.z + t4.z;
            y[3] = (oacc[i][3]-mu)*rstd*g4.w + t4.w;
            awrite(ecol, y);
        }
    }

    // ================= GEMM3: logits = y @ embed.T (unswapped) =================
    __syncthreads();
    #pragma unroll
    for (int k0 = 0; k0 < 8; ++k0) ab[k0] = afrag(k0);   // y fragments
    #pragma unroll
    for (int h = 0; h < 2; ++h){
        __syncthreads();
        stage(Eb + h*128*256);
        __syncthreads();
        #pragma unroll
        for (int n = 0; n < 8; ++n){
            f32x4 acc = {0.f,0.f,0.f,0.f};
            #pragma unroll
            for (int k0 = 0; k0 < 8; ++k0)
                acc = __builtin_amdgcn_mfma_f32_16x16x32_bf16(ab[k0], wfrag(n,k0), acc, 0,0,0);
            int v = h*128 + n*16 + lr;
            float* op = out + (m0 + wid*16 + lg*4)*256 + v;
            op[0]   = acc[0];
            op[256] = acc[1];
            op[512] = acc[2];
            op[768] = acc[3];
        }
    }
}

// --------------------------------------------------------------------------
extern "C" void kernel_launch(void* const* d_in, const int* in_sizes, int n_in,
                              void* d_out, int out_size, void* d_ws, size_t ws_size,
                              hipStream_t stream){
    const int*   idx   = (const int*)d_in[0];
    const float* embed = (const float*)d_in[1];
    const float* W_in  = (const float*)d_in[2];
    const float* W     = (const float*)d_in[3];
    const float* W1    = (const float*)d_in[4];
    const float* b1    = (const float*)d_in[5];
    const float* W2    = (const float*)d_in[6];
    const float* b2    = (const float*)d_in[7];
    const float* gamma = (const float*)d_in[8];
    const float* beta  = (const float*)d_in[9];

    char* ws = (char*)d_ws;
    float*  proj  = (float*)ws;                   // 256 KB fp32
    ushort* W1b   = (ushort*)(ws + 262144);       // 128 KB bf16
    ushort* W2b   = (ushort*)(ws + 393216);       // 128 KB
    ushort* Eb    = (ushort*)(ws + 524288);       // 128 KB
    float*  cval  = (float*)(ws + 655360);        // 56 KB
    int*    ccol  = (int*)(ws + 712704);          // 56 KB
    int*    cnt   = (int*)(ws + 770048);          // 1 KB
    int*    sperm = (int*)(ws + 771072);          // 1 KB
    ushort* hs    = (ushort*)(ws + 1048576);      // 134.2 MB bf16 [B*T, 256]
    if (ws_size < (size_t)135266304) return;      // ws too small -> recognizable absmax fail

    k_conv   <<<256, 256, 0, stream>>>(W1, W2, embed, W1b, W2b, Eb);
    k_proj   <<<256, 256, 0, stream>>>(embed, W_in, proj);
    k_csr    <<<256, 64, 0, stream>>>(W, cval, ccol, cnt);
    k_rank   <<<1, 256, 0, stream>>>(cnt, sperm);
    k_recur  <<<256, 512, 0, stream>>>(idx, cval, ccol, cnt, sperm, proj, hs);
    k_readout<<<2048, 512, 0, stream>>>(hs, W1b, W2b, Eb, b1, b2, gamma, beta, (float*)d_out);
}

// Round 11
// 555.858 us; speedup vs baseline: 3.1998x; 1.3524x over previous
//
#include <hip/hip_runtime.h>
#include <cstdint>

typedef __attribute__((ext_vector_type(8))) short short8;
typedef __attribute__((ext_vector_type(4))) float f32x4;

__device__ __forceinline__ ushort f2bf(float x){
    uint32_t u = __float_as_uint(x);
    u = (u + 0x7FFFu + ((u >> 16) & 1u)) >> 16;
    return (ushort)u;
}
__device__ __forceinline__ ushort f2h(float x){
    _Float16 h = (_Float16)x;
    return __builtin_bit_cast(ushort, h);
}

// -------- kernel 1: weight conversion (bf16 readout weights + fp16 W) -----
__global__ void k_conv(const float* __restrict__ W1, const float* __restrict__ W2,
                       const float* __restrict__ Emb, const float* __restrict__ W,
                       ushort* __restrict__ W1b, ushort* __restrict__ W2b,
                       ushort* __restrict__ Eb, ushort* __restrict__ Wh){
    int i = blockIdx.x * 256 + threadIdx.x;   // grid 256 -> 65536
    W1b[i] = f2bf(W1[i]);
    W2b[i] = f2bf(W2[i]);
    Eb[i]  = f2bf(Emb[i]);
    Wh[i]  = f2h(W[i]);
}

// -------- kernel 2: proj[v][h] = sum_e embed[v,e]*W_in[h,e]  (fp32) -------
__global__ void k_proj(const float* __restrict__ emb, const float* __restrict__ Win,
                       float* __restrict__ proj){
    __shared__ __align__(16) float se[256];
    int v = blockIdx.x, h = threadIdx.x;
    se[h] = emb[v*256 + h];
    __syncthreads();
    const float* wr = Win + h*256;
    float a0=0.f,a1=0.f,a2=0.f,a3=0.f;
    #pragma unroll
    for (int e = 0; e < 256; e += 4){
        float4 w = *(const float4*)(wr + e);
        a0 = fmaf(w.x, se[e+0], a0);
        a1 = fmaf(w.y, se[e+1], a1);
        a2 = fmaf(w.z, se[e+2], a2);
        a3 = fmaf(w.w, se[e+3], a3);
    }
    proj[v*256 + h] = (a0+a1)+(a2+a3);
}

// ------------- kernel 3: ESN recurrence via MFMA, fp16 W+state ------------
// 256 blocks = (segment s in [0,32)) x (batch group pg in [0,8), 16 batches).
// Segment s writes t in [64s, 64s+64); s>0 starts from h=0 at
// t0 = max(0, 64s-256): 256 warmup steps (contraction 0.97^256 ~ 4e-4,
// 3x below the h-quantization noise; rounds 9/10 proved warmup invisible).
// Critical path: 320 steps.
//
// Per step: H_t (16 batches x 256 hdim, fp16, LDS, XOR-swizzled ^(lr<<4)
// for conflict-free b128 B-frag reads) -> D[hdim,batch] = Wh @ H^T via
// mfma_f32_16x16x32_f16 -> fp32 epilogue (u add, clip, tanh, leak with
// fp32 h_prev in registers) -> write H_{t+1} (fp16 LDS) + hs (bf16 global).
// 512 threads = 8 waves, wave w owns hdim-tiles {2w, 2w+1}: A-frags (fp16 W
// rows) live in 64 VGPRs, loaded once. Layouts mirror the PASSING k_readout:
// A row = lane&15, k-offset (lane>>4)*16B; D col(batch) = lane&15,
// row = (lane>>4)*4+q (m89-verified).
// fp16-W precision: err 2^-12 rel -> steady-state h error ~3e-4 abs, below
// the bf16 hs floor; leak accum stays fp32.
__global__ __launch_bounds__(512, 2) void k_recur(const int* __restrict__ idx,
        const ushort* Wh, const float* proj, ushort* hs){
    __shared__ __align__(16) char Hl[2][8192];   // fp16 H[16][256], dbuf, swizzled
    const int tid  = threadIdx.x;
    const int wid  = tid >> 6;
    const int lane = tid & 63;
    const int lr   = lane & 15;        // batch col / A-row-in-tile
    const int lg   = lane >> 4;
    const int seg  = blockIdx.x >> 3;  // time segment 0..31
    const int pg   = blockIdx.x & 7;   // batch group 0..7
    const int t0   = (64*seg - 256 > 0) ? (64*seg - 256) : 0;
    const int t1   = 64*seg + 64;
    const int tw   = 64*seg;           // first written step

    // A-frags: W rows for tiles n0=2*wid, n1=2*wid+1 (fp16, 16 frags = 64 VGPR)
    short8 A0[8], A1[8];
    {
        const char* wb = (const char*)Wh + (32*wid + lr)*512 + lg*16;
        #pragma unroll
        for (int kk = 0; kk < 8; ++kk){
            A0[kk] = __builtin_bit_cast(short8, *(const uint4*)(wb + kk*64));
            A1[kk] = __builtin_bit_cast(short8, *(const uint4*)(wb + 16*512 + kk*64));
        }
    }

    char* Hb = &Hl[0][0];
    *(uint4*)(Hb + tid*16) = uint4{0,0,0,0};     // zero buffer 0 (8 KB)
    __syncthreads();

    const int mybat = pg*16 + lr;
    const int64_t idxbase = (int64_t)mybat * 2048;
    ushort* hsrow = hs + (size_t)mybat * 2048 * 256;
    const int hd0 = 32*wid + lg*4;               // tile0 quad base hdim
    const int hd1 = hd0 + 16;

    float hp0[4] = {0.f,0.f,0.f,0.f}, hp1[4] = {0.f,0.f,0.f,0.f};

    // prologue: u for t0, token for t0+1
    int tok  = idx[idxbase + t0];
    int tok2 = idx[idxbase + ((t0+1 < 2048) ? t0+1 : 2047)];
    f32x4 u0 = *(const f32x4*)(proj + tok*256 + hd0);
    f32x4 u1 = *(const f32x4*)(proj + tok*256 + hd1);

#define STEP(T, RO, WO)                                                        \
    {                                                                          \
        int tok3 = idx[idxbase + (((T)+2 < 2048) ? (T)+2 : 2047)];             \
        f32x4 ac0 = {0.f,0.f,0.f,0.f}, ac1 = {0.f,0.f,0.f,0.f};                \
        _Pragma("unroll")                                                      \
        for (int kk = 0; kk < 8; ++kk){                                        \
            int ra = ((RO) + lr*512 + kk*64 + lg*16) ^ (lr << 4);              \
            short8 Bf = __builtin_bit_cast(short8, *(const uint4*)(Hb + ra));  \
            ac0 = __builtin_amdgcn_mfma_f32_16x16x32_f16(A0[kk], Bf, ac0, 0,0,0);\
            ac1 = __builtin_amdgcn_mfma_f32_16x16x32_f16(A1[kk], Bf, ac1, 0,0,0);\
        }                                                                      \
        f32x4 u0n = *(const f32x4*)(proj + tok2*256 + hd0);                    \
        f32x4 u1n = *(const f32x4*)(proj + tok2*256 + hd1);                    \
        ushort ph0[4], ph1[4], sb0[4], sb1[4];                                 \
        _Pragma("unroll")                                                      \
        for (int q = 0; q < 4; ++q){                                           \
            float pre = ac0[q] + u0[q];                                        \
            pre = fminf(20.f, fmaxf(-20.f, pre));                              \
            float e  = __expf(2.f*pre);                                        \
            float th = 1.f - __fdividef(2.f, e + 1.f);                         \
            float hn = 0.7f*hp0[q] + 0.3f*th;                                  \
            hp0[q] = hn; ph0[q] = f2h(hn); sb0[q] = f2bf(hn);                  \
            pre = ac1[q] + u1[q];                                              \
            pre = fminf(20.f, fmaxf(-20.f, pre));                              \
            e  = __expf(2.f*pre);                                              \
            th = 1.f - __fdividef(2.f, e + 1.f);                               \
            hn = 0.7f*hp1[q] + 0.3f*th;                                        \
            hp1[q] = hn; ph1[q] = f2h(hn); sb1[q] = f2bf(hn);                  \
        }                                                                      \
        int wa0 = ((WO) + lr*512 + hd0*2) ^ (lr << 4);                         \
        int wa1 = ((WO) + lr*512 + hd1*2) ^ (lr << 4);                         \
        *(ushort4*)(Hb + wa0) = ushort4{ph0[0], ph0[1], ph0[2], ph0[3]};       \
        *(ushort4*)(Hb + wa1) = ushort4{ph1[0], ph1[1], ph1[2], ph1[3]};       \
        if ((T) >= tw){                                                        \
            *(ushort4*)(hsrow + (size_t)(T)*256 + hd0) =                       \
                ushort4{sb0[0], sb0[1], sb0[2], sb0[3]};                       \
            *(ushort4*)(hsrow + (size_t)(T)*256 + hd1) =                       \
                ushort4{sb1[0], sb1[1], sb1[2], sb1[3]};                       \
        }                                                                      \
        u0 = u0n; u1 = u1n; tok2 = tok3;                                       \
        asm volatile("s_waitcnt lgkmcnt(0)\n\ts_barrier" ::: "memory");        \
    }

    for (int t = t0; t < t1; t += 2){
        STEP(t,   0,    8192);
        STEP(t+1, 8192, 0);
    }
#undef STEP
}

// ---------------- kernel 4: fused readout MLP + LN + lm_head --------------
// per block: 128 rows of BT. 512 threads = 8 waves, wave owns 16 rows.
// GEMM1 (swapped, D[e,m]) -> gelu -> A1_lds[m][e]
// GEMM2 (swapped, D[e2,m]) -> LN over e2 -> y_lds[m][e2] (overwrites A1)
// GEMM3 (unswapped, D[m,v]) -> fp32 out
__global__ __launch_bounds__(512) void k_readout(
        const ushort* __restrict__ hs,
        const ushort* __restrict__ W1b, const ushort* __restrict__ W2b,
        const ushort* __restrict__ Eb,
        const float* __restrict__ b1, const float* __restrict__ b2,
        const float* __restrict__ gamma, const float* __restrict__ beta,
        float* __restrict__ out){
    __shared__ __align__(16) char w_lds[65536];   // staged weight half: 128 rows x 256 bf16
    __shared__ __align__(16) char a_lds[65536];   // A1 / y tile: 128 rows x 256 bf16

    const int tid  = threadIdx.x;
    const int wid  = tid >> 6;
    const int lane = tid & 63;
    const int lr   = lane & 15;
    const int lg   = lane >> 4;
    const size_t m0 = (size_t)blockIdx.x * 128;
    const int ml   = wid*16 + lr;                 // this lane's m-row (local)

    // stage a 128x256 bf16 weight half into w_lds, XOR-swizzled
    auto stage = [&](const ushort* src){
        #pragma unroll
        for (int i = 0; i < 8; ++i){
            int off = (i*512 + tid) * 16;
            uint4 v = *(const uint4*)((const char*)src + off);
            int row = off >> 9;
            *(uint4*)(w_lds + (off ^ ((row & 7) << 4))) = v;
        }
    };
    // A-fragment of staged weight, tile n, k-chunk k0
    auto wfrag = [&](int n, int k0) -> short8 {
        int row  = n*16 + lr;
        int addr = (row << 9) + k0*64 + lg*16;
        addr ^= (row & 7) << 4;
        return __builtin_bit_cast(short8, *(const uint4*)(w_lds + addr));
    };
    // fragment of a_lds at own m-row, k-chunk k0
    auto afrag = [&](int k0) -> short8 {
        int addr = (ml << 9) + k0*64 + lg*16;
        addr ^= (ml & 7) << 4;
        return __builtin_bit_cast(short8, *(const uint4*)(a_lds + addr));
    };
    // write 4 consecutive e-values (8B) into a_lds[ml][ecol..ecol+3]
    auto awrite = [&](int ecol, f32x4 v){
        ushort4 pk;
        pk.x = f2bf(v[0]); pk.y = f2bf(v[1]); pk.z = f2bf(v[2]); pk.w = f2bf(v[3]);
        int addr = (ml << 9) + ecol*2;
        addr ^= (ml & 7) << 4;
        *(ushort4*)(a_lds + addr) = pk;
    };

    // ---- hs fragments straight from global (16B/lane, reused both halves) ----
    short8 hb[8];
    {
        const char* p = (const char*)(hs + (m0 + ml)*256) + lg*16;
        #pragma unroll
        for (int k0 = 0; k0 < 8; ++k0)
            hb[k0] = __builtin_bit_cast(short8, *(const uint4*)(p + k0*64));
    }

    // ================= GEMM1: A1 = gelu(hs @ W1.T + b1) =================
    #pragma unroll
    for (int h = 0; h < 2; ++h){
        __syncthreads();
        stage(W1b + h*128*256);
        __syncthreads();
        #pragma unroll
        for (int n = 0; n < 8; ++n){
            int eb = h*128 + n*16;
            float4 bi = *(const float4*)(b1 + eb + lg*4);
            f32x4 acc = {bi.x, bi.y, bi.z, bi.w};
            #pragma unroll
            for (int k0 = 0; k0 < 8; ++k0)
                acc = __builtin_amdgcn_mfma_f32_16x16x32_bf16(wfrag(n,k0), hb[k0], acc, 0,0,0);
            f32x4 g;
            #pragma unroll
            for (int q = 0; q < 4; ++q){
                float x = acc[q];
                g[q] = 0.5f*x*(1.f + erff(x*0.70710678118654752440f));
            }
            awrite(eb + lg*4, g);
        }
    }

    // ================= GEMM2: o = A1 @ W2.T + b2 =================
    short8 ab[8];
    __syncthreads();
    #pragma unroll
    for (int k0 = 0; k0 < 8; ++k0) ab[k0] = afrag(k0);
    f32x4 oacc[16];
    #pragma unroll
    for (int h = 0; h < 2; ++h){
        __syncthreads();
        stage(W2b + h*128*256);
        __syncthreads();
        #pragma unroll
        for (int n = 0; n < 8; ++n){
            int eb = h*128 + n*16;
            float4 bi = *(const float4*)(b2 + eb + lg*4);
            f32x4 acc = {bi.x, bi.y, bi.z, bi.w};
            #pragma unroll
            for (int k0 = 0; k0 < 8; ++k0)
                acc = __builtin_amdgcn_mfma_f32_16x16x32_bf16(wfrag(n,k0), ab[k0], acc, 0,0,0);
            oacc[h*8+n] = acc;
        }
    }

    // ================= LayerNorm over e2 (row dim of swapped D2) =================
    {
        float sum = 0.f, ss = 0.f;
        #pragma unroll
        for (int i = 0; i < 16; ++i){
            #pragma unroll
            for (int q = 0; q < 4; ++q){ float x = oacc[i][q]; sum += x; ss += x*x; }
        }
        sum += __shfl_xor(sum, 16); ss += __shfl_xor(ss, 16);
        sum += __shfl_xor(sum, 32); ss += __shfl_xor(ss, 32);
        float mu   = sum * (1.f/256.f);
        float var  = ss * (1.f/256.f) - mu*mu;
        float rstd = rsqrtf(var + 1e-5f);
        #pragma unroll
        for (int i = 0; i < 16; ++i){
            int ecol = (i >> 3)*128 + (i & 7)*16 + lg*4;
            float4 g4 = *(const float4*)(gamma + ecol);
            float4 t4 = *(const float4*)(beta + ecol);
            f32x4 y;
            y[0] = (oacc[i][0]-mu)*rstd*g4.x + t4.x;
            y[1] = (oacc[i][1]-mu)*rstd*g4.y + t4.y;
            y[2] = (oacc[i][2]-mu)*rstd*g4.z + t4.z;
            y[3] = (oacc[i][3]-mu)*rstd*g4.w + t4.w;
            awrite(ecol, y);
        }
    }

    // ================= GEMM3: logits = y @ embed.T (unswapped) =================
    __syncthreads();
    #pragma unroll
    for (int k0 = 0; k0 < 8; ++k0) ab[k0] = afrag(k0);   // y fragments
    #pragma unroll
    for (int h = 0; h < 2; ++h){
        __syncthreads();
        stage(Eb + h*128*256);
        __syncthreads();
        #pragma unroll
        for (int n = 0; n < 8; ++n){
            f32x4 acc = {0.f,0.f,0.f,0.f};
            #pragma unroll
            for (int k0 = 0; k0 < 8; ++k0)
                acc = __builtin_amdgcn_mfma_f32_16x16x32_bf16(ab[k0], wfrag(n,k0), acc, 0,0,0);
            int v = h*128 + n*16 + lr;
            float* op = out + (m0 + wid*16 + lg*4)*256 + v;
            op[0]   = acc[0];
            op[256] = acc[1];
            op[512] = acc[2];
            op[768] = acc[3];
        }
    }
}

// --------------------------------------------------------------------------
extern "C" void kernel_launch(void* const* d_in, const int* in_sizes, int n_in,
                              void* d_out, int out_size, void* d_ws, size_t ws_size,
                              hipStream_t stream){
    const int*   idx   = (const int*)d_in[0];
    const float* embed = (const float*)d_in[1];
    const float* W_in  = (const float*)d_in[2];
    const float* W     = (const float*)d_in[3];
    const float* W1    = (const float*)d_in[4];
    const float* b1    = (const float*)d_in[5];
    const float* W2    = (const float*)d_in[6];
    const float* b2    = (const float*)d_in[7];
    const float* gamma = (const float*)d_in[8];
    const float* beta  = (const float*)d_in[9];

    char* ws = (char*)d_ws;
    float*  proj  = (float*)ws;                   // 256 KB fp32
    ushort* W1b   = (ushort*)(ws + 262144);       // 128 KB bf16
    ushort* W2b   = (ushort*)(ws + 393216);       // 128 KB
    ushort* Eb    = (ushort*)(ws + 524288);       // 128 KB
    ushort* Wh    = (ushort*)(ws + 655360);       // 128 KB fp16 W
    ushort* hs    = (ushort*)(ws + 1048576);      // 134.2 MB bf16 [B*T, 256]
    if (ws_size < (size_t)135266304) return;      // ws too small -> recognizable absmax fail

    k_conv   <<<256, 256, 0, stream>>>(W1, W2, embed, W, W1b, W2b, Eb, Wh);
    k_proj   <<<256, 256, 0, stream>>>(embed, W_in, proj);
    k_recur  <<<256, 512, 0, stream>>>(idx, Wh, proj, hs);
    k_readout<<<2048, 512, 0, stream>>>(hs, W1b, W2b, Eb, b1, b2, gamma, beta, (float*)d_out);
}

// Round 12
// 443.717 us; speedup vs baseline: 4.0085x; 1.2527x over previous
//
#include <hip/hip_runtime.h>
#include <cstdint>

typedef __attribute__((ext_vector_type(8))) short short8;
typedef __attribute__((ext_vector_type(4))) float f32x4;

__device__ __forceinline__ ushort f2bf(float x){
    uint32_t u = __float_as_uint(x);
    u = (u + 0x7FFFu + ((u >> 16) & 1u)) >> 16;
    return (ushort)u;
}
__device__ __forceinline__ ushort f2h(float x){
    _Float16 h = (_Float16)x;
    return __builtin_bit_cast(ushort, h);
}

// -------- kernel 1: weight conversion (fp16 W + W1, bf16 W2 + embed) ------
__global__ void k_conv(const float* __restrict__ W1, const float* __restrict__ W2,
                       const float* __restrict__ Emb, const float* __restrict__ W,
                       ushort* __restrict__ W1h, ushort* __restrict__ W2b,
                       ushort* __restrict__ Eb, ushort* __restrict__ Wh){
    int i = blockIdx.x * 256 + threadIdx.x;   // grid 256 -> 65536
    W1h[i] = f2h(W1[i]);
    W2b[i] = f2bf(W2[i]);
    Eb[i]  = f2bf(Emb[i]);
    Wh[i]  = f2h(W[i]);
}

// -------- kernel 2: proj[v][h] = sum_e embed[v,e]*W_in[h,e]  (fp32) -------
__global__ void k_proj(const float* __restrict__ emb, const float* __restrict__ Win,
                       float* __restrict__ proj){
    __shared__ __align__(16) float se[256];
    int v = blockIdx.x, h = threadIdx.x;
    se[h] = emb[v*256 + h];
    __syncthreads();
    const float* wr = Win + h*256;
    float a0=0.f,a1=0.f,a2=0.f,a3=0.f;
    #pragma unroll
    for (int e = 0; e < 256; e += 4){
        float4 w = *(const float4*)(wr + e);
        a0 = fmaf(w.x, se[e+0], a0);
        a1 = fmaf(w.y, se[e+1], a1);
        a2 = fmaf(w.z, se[e+2], a2);
        a3 = fmaf(w.w, se[e+3], a3);
    }
    proj[v*256 + h] = (a0+a1)+(a2+a3);
}

// ------------- kernel 3: ESN recurrence via MFMA, fp16 W+state ------------
// 256 blocks = (segment s in [0,32)) x (batch group pg in [0,8), 16 batches).
// Segment s writes t in [64s, 64s+64); s>0 starts from h=0 at
// t0 = max(0, 64s-192): 192 warmup steps (worst-case contraction 0.97^192
// ~ 3e-3 x |h| ~ 1e-3, below the fp16/bf16 quantization noise; empirical
// decay much faster - rounds 9-11 all pinned at the quantization floor).
// Critical path: 256 steps.
//
// Per step: H_t (16 batches x 256 hdim, fp16, LDS, XOR-swizzled ^(lr<<4))
// -> D[hdim,batch] = Wh @ H^T via mfma_f32_16x16x32_f16 with C INITIALIZED
// to u (input projection - saves the add) -> fused epilogue per value:
// e=exp2(pre*2log2e); r=rcp(e+1); hn=fma(.7,hp,fma(-.6,r,.3))  [no clamp:
// the rational form saturates correctly for |pre|>20] -> cvt_pkrtz packs
// 2 f32 -> 2 fp16 in ONE instr, the same packed word feeds the LDS H-write
// AND the global hs store (hs is now fp16; readout GEMM1 runs f16 MFMA).
// Layouts identical to round 11 (HW-verified).
__global__ __launch_bounds__(512, 2) void k_recur(const int* __restrict__ idx,
        const ushort* Wh, const float* proj, ushort* hs){
    __shared__ __align__(16) char Hl[2][8192];   // fp16 H[16][256], dbuf, swizzled
    const int tid  = threadIdx.x;
    const int wid  = tid >> 6;
    const int lane = tid & 63;
    const int lr   = lane & 15;        // batch col / A-row-in-tile
    const int lg   = lane >> 4;
    const int seg  = blockIdx.x >> 3;  // time segment 0..31
    const int pg   = blockIdx.x & 7;   // batch group 0..7
    const int t0   = (64*seg - 192 > 0) ? (64*seg - 192) : 0;
    const int t1   = 64*seg + 64;
    const int tw   = 64*seg;           // first written step

    // A-frags: W rows for tiles n0=2*wid, n1=2*wid+1 (fp16, 16 frags = 64 VGPR)
    short8 A0[8], A1[8];
    {
        const char* wb = (const char*)Wh + (32*wid + lr)*512 + lg*16;
        #pragma unroll
        for (int kk = 0; kk < 8; ++kk){
            A0[kk] = __builtin_bit_cast(short8, *(const uint4*)(wb + kk*64));
            A1[kk] = __builtin_bit_cast(short8, *(const uint4*)(wb + 16*512 + kk*64));
        }
    }

    char* Hb = &Hl[0][0];
    *(uint4*)(Hb + tid*16) = uint4{0,0,0,0};     // zero buffer 0 (8 KB)
    __syncthreads();

    const int mybat = pg*16 + lr;
    const int64_t idxbase = (int64_t)mybat * 2048;
    ushort* hsrow = hs + (size_t)mybat * 2048 * 256;
    const int hd0 = 32*wid + lg*4;               // tile0 quad base hdim
    const int hd1 = hd0 + 16;

    float hp0[4] = {0.f,0.f,0.f,0.f}, hp1[4] = {0.f,0.f,0.f,0.f};

    // prologue: u for t0, token for t0+1
    int tok  = idx[idxbase + t0];
    int tok2 = idx[idxbase + ((t0+1 < 2048) ? t0+1 : 2047)];
    f32x4 u0 = *(const f32x4*)(proj + tok*256 + hd0);
    f32x4 u1 = *(const f32x4*)(proj + tok*256 + hd1);

#define STEP(T, RO, WO)                                                        \
    {                                                                          \
        int tok3 = idx[idxbase + (((T)+2 < 2048) ? (T)+2 : 2047)];             \
        f32x4 ac0 = u0, ac1 = u1;   /* C-init = input projection */            \
        _Pragma("unroll")                                                      \
        for (int kk = 0; kk < 8; ++kk){                                        \
            int ra = ((RO) + lr*512 + kk*64 + lg*16) ^ (lr << 4);              \
            short8 Bf = __builtin_bit_cast(short8, *(const uint4*)(Hb + ra));  \
            ac0 = __builtin_amdgcn_mfma_f32_16x16x32_f16(A0[kk], Bf, ac0, 0,0,0);\
            ac1 = __builtin_amdgcn_mfma_f32_16x16x32_f16(A1[kk], Bf, ac1, 0,0,0);\
        }                                                                      \
        f32x4 u0n = *(const f32x4*)(proj + tok2*256 + hd0);                    \
        f32x4 u1n = *(const f32x4*)(proj + tok2*256 + hd1);                    \
        float hn0[4], hn1[4];                                                  \
        _Pragma("unroll")                                                      \
        for (int q = 0; q < 4; ++q){                                           \
            float e0 = __builtin_amdgcn_exp2f(ac0[q] * 2.8853900817779268f);   \
            float r0 = __builtin_amdgcn_rcpf(e0 + 1.f);                        \
            hn0[q] = fmaf(0.7f, hp0[q], fmaf(-0.6f, r0, 0.3f));                \
            hp0[q] = hn0[q];                                                   \
            float e1 = __builtin_amdgcn_exp2f(ac1[q] * 2.8853900817779268f);   \
            float r1 = __builtin_amdgcn_rcpf(e1 + 1.f);                        \
            hn1[q] = fmaf(0.7f, hp1[q], fmaf(-0.6f, r1, 0.3f));                \
            hp1[q] = hn1[q];                                                   \
        }                                                                      \
        uint2 pk0, pk1;                                                        \
        pk0.x = __builtin_bit_cast(uint, __builtin_amdgcn_cvt_pkrtz(hn0[0], hn0[1])); \
        pk0.y = __builtin_bit_cast(uint, __builtin_amdgcn_cvt_pkrtz(hn0[2], hn0[3])); \
        pk1.x = __builtin_bit_cast(uint, __builtin_amdgcn_cvt_pkrtz(hn1[0], hn1[1])); \
        pk1.y = __builtin_bit_cast(uint, __builtin_amdgcn_cvt_pkrtz(hn1[2], hn1[3])); \
        int wa0 = ((WO) + lr*512 + hd0*2) ^ (lr << 4);                         \
        int wa1 = ((WO) + lr*512 + hd1*2) ^ (lr << 4);                         \
        *(uint2*)(Hb + wa0) = pk0;                                             \
        *(uint2*)(Hb + wa1) = pk1;                                             \
        if ((T) >= tw){                                                        \
            *(uint2*)(hsrow + (size_t)(T)*256 + hd0) = pk0;                    \
            *(uint2*)(hsrow + (size_t)(T)*256 + hd1) = pk1;                    \
        }                                                                      \
        u0 = u0n; u1 = u1n; tok2 = tok3;                                       \
        asm volatile("s_waitcnt lgkmcnt(0)\n\ts_barrier" ::: "memory");        \
    }

    for (int t = t0; t < t1; t += 2){
        STEP(t,   0,    8192);
        STEP(t+1, 8192, 0);
    }
#undef STEP
}

// ---------------- kernel 4: fused readout MLP + LN + lm_head --------------
// per block: 128 rows of BT. 512 threads = 8 waves, wave owns 16 rows.
// GEMM1 (fp16 in: hs + W1h, swapped, D[e,m]) -> gelu -> A1_lds[m][e] bf16
// GEMM2 (bf16, swapped, D[e2,m]) -> LN over e2 -> y_lds[m][e2]
// GEMM3 (bf16, unswapped, D[m,v]) -> fp32 out
__global__ __launch_bounds__(512) void k_readout(
        const ushort* __restrict__ hs,
        const ushort* __restrict__ W1h, const ushort* __restrict__ W2b,
        const ushort* __restrict__ Eb,
        const float* __restrict__ b1, const float* __restrict__ b2,
        const float* __restrict__ gamma, const float* __restrict__ beta,
        float* __restrict__ out){
    __shared__ __align__(16) char w_lds[65536];   // staged weight half: 128 rows x 256
    __shared__ __align__(16) char a_lds[65536];   // A1 / y tile: 128 rows x 256 bf16

    const int tid  = threadIdx.x;
    const int wid  = tid >> 6;
    const int lane = tid & 63;
    const int lr   = lane & 15;
    const int lg   = lane >> 4;
    const size_t m0 = (size_t)blockIdx.x * 128;
    const int ml   = wid*16 + lr;                 // this lane's m-row (local)

    // stage a 128x256 2-byte weight half into w_lds, XOR-swizzled
    auto stage = [&](const ushort* src){
        #pragma unroll
        for (int i = 0; i < 8; ++i){
            int off = (i*512 + tid) * 16;
            uint4 v = *(const uint4*)((const char*)src + off);
            int row = off >> 9;
            *(uint4*)(w_lds + (off ^ ((row & 7) << 4))) = v;
        }
    };
    // A-fragment of staged weight, tile n, k-chunk k0
    auto wfrag = [&](int n, int k0) -> short8 {
        int row  = n*16 + lr;
        int addr = (row << 9) + k0*64 + lg*16;
        addr ^= (row & 7) << 4;
        return __builtin_bit_cast(short8, *(const uint4*)(w_lds + addr));
    };
    // fragment of a_lds at own m-row, k-chunk k0
    auto afrag = [&](int k0) -> short8 {
        int addr = (ml << 9) + k0*64 + lg*16;
        addr ^= (ml & 7) << 4;
        return __builtin_bit_cast(short8, *(const uint4*)(a_lds + addr));
    };
    // write 4 consecutive e-values (8B) into a_lds[ml][ecol..ecol+3]
    auto awrite = [&](int ecol, f32x4 v){
        ushort4 pk;
        pk.x = f2bf(v[0]); pk.y = f2bf(v[1]); pk.z = f2bf(v[2]); pk.w = f2bf(v[3]);
        int addr = (ml << 9) + ecol*2;
        addr ^= (ml & 7) << 4;
        *(ushort4*)(a_lds + addr) = pk;
    };

    // ---- hs fragments straight from global (fp16, 16B/lane, reused twice) ----
    short8 hb[8];
    {
        const char* p = (const char*)(hs + (m0 + ml)*256) + lg*16;
        #pragma unroll
        for (int k0 = 0; k0 < 8; ++k0)
            hb[k0] = __builtin_bit_cast(short8, *(const uint4*)(p + k0*64));
    }

    // ================= GEMM1 (fp16): A1 = gelu(hs @ W1.T + b1) =================
    #pragma unroll
    for (int h = 0; h < 2; ++h){
        __syncthreads();
        stage(W1h + h*128*256);
        __syncthreads();
        #pragma unroll
        for (int n = 0; n < 8; ++n){
            int eb = h*128 + n*16;
            float4 bi = *(const float4*)(b1 + eb + lg*4);
            f32x4 acc = {bi.x, bi.y, bi.z, bi.w};
            #pragma unroll
            for (int k0 = 0; k0 < 8; ++k0)
                acc = __builtin_amdgcn_mfma_f32_16x16x32_f16(wfrag(n,k0), hb[k0], acc, 0,0,0);
            f32x4 g;
            #pragma unroll
            for (int q = 0; q < 4; ++q){
                float x = acc[q];
                g[q] = 0.5f*x*(1.f + erff(x*0.70710678118654752440f));
            }
            awrite(eb + lg*4, g);
        }
    }

    // ================= GEMM2 (bf16): o = A1 @ W2.T + b2 =================
    short8 ab[8];
    __syncthreads();
    #pragma unroll
    for (int k0 = 0; k0 < 8; ++k0) ab[k0] = afrag(k0);
    f32x4 oacc[16];
    #pragma unroll
    for (int h = 0; h < 2; ++h){
        __syncthreads();
        stage(W2b + h*128*256);
        __syncthreads();
        #pragma unroll
        for (int n = 0; n < 8; ++n){
            int eb = h*128 + n*16;
            float4 bi = *(const float4*)(b2 + eb + lg*4);
            f32x4 acc = {bi.x, bi.y, bi.z, bi.w};
            #pragma unroll
            for (int k0 = 0; k0 < 8; ++k0)
                acc = __builtin_amdgcn_mfma_f32_16x16x32_bf16(wfrag(n,k0), ab[k0], acc, 0,0,0);
            oacc[h*8+n] = acc;
        }
    }

    // ================= LayerNorm over e2 (row dim of swapped D2) =================
    {
        float sum = 0.f, ss = 0.f;
        #pragma unroll
        for (int i = 0; i < 16; ++i){
            #pragma unroll
            for (int q = 0; q < 4; ++q){ float x = oacc[i][q]; sum += x; ss += x*x; }
        }
        sum += __shfl_xor(sum, 16); ss += __shfl_xor(ss, 16);
        sum += __shfl_xor(sum, 32); ss += __shfl_xor(ss, 32);
        float mu   = sum * (1.f/256.f);
        float var  = ss * (1.f/256.f) - mu*mu;
        float rstd = rsqrtf(var + 1e-5f);
        #pragma unroll
        for (int i = 0; i < 16; ++i){
            int ecol = (i >> 3)*128 + (i & 7)*16 + lg*4;
            float4 g4 = *(const float4*)(gamma + ecol);
            float4 t4 = *(const float4*)(beta + ecol);
            f32x4 y;
            y[0] = (oacc[i][0]-mu)*rstd*g4.x + t4.x;
            y[1] = (oacc[i][1]-mu)*rstd*g4.y + t4.y;
            y[2] = (oacc[i][2]-mu)*rstd*g4.z + t4.z;
            y[3] = (oacc[i][3]-mu)*rstd*g4.w + t4.w;
            awrite(ecol, y);
        }
    }

    // ================= GEMM3 (bf16): logits = y @ embed.T =================
    __syncthreads();
    #pragma unroll
    for (int k0 = 0; k0 < 8; ++k0) ab[k0] = afrag(k0);   // y fragments
    #pragma unroll
    for (int h = 0; h < 2; ++h){
        __syncthreads();
        stage(Eb + h*128*256);
        __syncthreads();
        #pragma unroll
        for (int n = 0; n < 8; ++n){
            f32x4 acc = {0.f,0.f,0.f,0.f};
            #pragma unroll
            for (int k0 = 0; k0 < 8; ++k0)
                acc = __builtin_amdgcn_mfma_f32_16x16x32_bf16(ab[k0], wfrag(n,k0), acc, 0,0,0);
            int v = h*128 + n*16 + lr;
            float* op = out + (m0 + wid*16 + lg*4)*256 + v;
            op[0]   = acc[0];
            op[256] = acc[1];
            op[512] = acc[2];
            op[768] = acc[3];
        }
    }
}

// --------------------------------------------------------------------------
extern "C" void kernel_launch(void* const* d_in, const int* in_sizes, int n_in,
                              void* d_out, int out_size, void* d_ws, size_t ws_size,
                              hipStream_t stream){
    const int*   idx   = (const int*)d_in[0];
    const float* embed = (const float*)d_in[1];
    const float* W_in  = (const float*)d_in[2];
    const float* W     = (const float*)d_in[3];
    const float* W1    = (const float*)d_in[4];
    const float* b1    = (const float*)d_in[5];
    const float* W2    = (const float*)d_in[6];
    const float* b2    = (const float*)d_in[7];
    const float* gamma = (const float*)d_in[8];
    const float* beta  = (const float*)d_in[9];

    char* ws = (char*)d_ws;
    float*  proj  = (float*)ws;                   // 256 KB fp32
    ushort* W1h   = (ushort*)(ws + 262144);       // 128 KB fp16
    ushort* W2b   = (ushort*)(ws + 393216);       // 128 KB bf16
    ushort* Eb    = (ushort*)(ws + 524288);       // 128 KB bf16
    ushort* Wh    = (ushort*)(ws + 655360);       // 128 KB fp16 W
    ushort* hs    = (ushort*)(ws + 1048576);      // 134.2 MB fp16 [B*T, 256]
    if (ws_size < (size_t)135266304) return;      // ws too small -> recognizable absmax fail

    k_conv   <<<256, 256, 0, stream>>>(W1, W2, embed, W, W1h, W2b, Eb, Wh);
    k_proj   <<<256, 256, 0, stream>>>(embed, W_in, proj);
    k_recur  <<<256, 512, 0, stream>>>(idx, Wh, proj, hs);
    k_readout<<<2048, 512, 0, stream>>>(hs, W1h, W2b, Eb, b1, b2, gamma, beta, (float*)d_out);
}